// Round 1
// 573.849 us; speedup vs baseline: 1.2150x; 1.2150x over previous
//
#include <hip/hip_runtime.h>

typedef _Float16 half2v __attribute__((ext_vector_type(2)));
typedef _Float16 f16x8  __attribute__((ext_vector_type(8)));
typedef float    f32x4  __attribute__((ext_vector_type(4)));

#define T_LEN 1024
#define NBATCH 1024
#define HID 20
#define G_B 2       // batch elements per wave (lane groups of 20)
#define STEPS 8     // timesteps per superstep (one barrier per STEPS steps)
#define RSLOT 64    // halfs per ring timestep slot (2 batches x 32, zero-padded k=20..31)
#define PPITCH 84   // pre-gate LDS buffer row pitch in dwords (80 + 4 pad)

#if defined(__has_builtin)
#if __has_builtin(__builtin_amdgcn_fdot2)
#define HAVE_FDOT2 1
#endif
#endif

#define NLOG2E  -1.4426950408889634f   // -log2(e):  sigmoid gates
#define N2LOG2E -2.8853900817779268f   // -2log2(e): tanh gates

__device__ __forceinline__ float fdot2_(half2v a, half2v b, float c) {
#ifdef HAVE_FDOT2
    return __builtin_amdgcn_fdot2(a, b, c, false);
#else
    return c + (float)a[0] * (float)b[0] + (float)a[1] * (float)b[1];
#endif
}

__device__ __forceinline__ half2v pack2(float a, float b) {
    half2v r; r[0] = (_Float16)a; r[1] = (_Float16)b; return r;
}

// Load 20 f16 (one 32-half / 64B row, 16B-aligned) into 10 half2.
__device__ __forceinline__ void load_h20(const _Float16* row, half2v hp[10]) {
    uint4 q0 = *(const uint4*)(row);
    uint4 q1 = *(const uint4*)(row + 8);
    uint2 q2 = *(const uint2*)(row + 16);
    hp[0] = __builtin_bit_cast(half2v, q0.x);
    hp[1] = __builtin_bit_cast(half2v, q0.y);
    hp[2] = __builtin_bit_cast(half2v, q0.z);
    hp[3] = __builtin_bit_cast(half2v, q0.w);
    hp[4] = __builtin_bit_cast(half2v, q1.x);
    hp[5] = __builtin_bit_cast(half2v, q1.y);
    hp[6] = __builtin_bit_cast(half2v, q1.z);
    hp[7] = __builtin_bit_cast(half2v, q1.w);
    hp[8] = __builtin_bit_cast(half2v, q2.x);
    hp[9] = __builtin_bit_cast(half2v, q2.y);
}

// 20-element dot, two independent depth-5 chains, seeded with `seed`.
__device__ __forceinline__ float dot20s(const half2v W[10], const half2v h[10],
                                        float seed) {
    float a0 = seed, a1 = 0.f;
#pragma unroll
    for (int k = 0; k < 5; ++k) {
        a0 = fdot2_(W[k],     h[k],     a0);
        a1 = fdot2_(W[k + 5], h[k + 5], a1);
    }
    return a0 + a1;
}

// R16: replace the hoisted per-superstep ih-dot block (8 steps x 4 gates x
// dot20 = 352 VALU / wave) with ONE mfma_f32_16x16x32_f16 per 16-col tile:
//   A = below-ring rows: 16 rows = (step i, batch g), K=32 (h padded w/ 0)
//   B = W_ih pre-scaled f16 fragments (lane&15 = gate-unit col, lane>>4 = k-chunk)
//   C scatter (col=lane&15, row=(lane>>4)*4+q) -> per-wave LDS pre buffer,
// serial phase reads 4 dwords/step. Activation math & own-h fdot2 chain
// unchanged from R15 (shared-rcp, 8 trans/step). oA carry unified:
// oA = bias + Whh.h(t) computed right after each h write; pre-gate seed is
// oA + ih-contribution (identical algebra to R15).
__global__ void __launch_bounds__(192, 2) lstm3_r16(
    const float* __restrict__ x,
    const float* __restrict__ wih0, const float* __restrict__ whh0,
    const float* __restrict__ bih0, const float* __restrict__ bhh0,
    const float* __restrict__ wih1, const float* __restrict__ whh1,
    const float* __restrict__ bih1, const float* __restrict__ bhh1,
    const float* __restrict__ wih2, const float* __restrict__ whh2,
    const float* __restrict__ bih2, const float* __restrict__ bhh2,
    const float* __restrict__ fcw, const float* __restrict__ fcb,
    float* __restrict__ out)
{
    __shared__ __align__(16) float xlds[G_B * T_LEN];           // interleaved [t][g]
    __shared__ __align__(16) _Float16 rings[3][2 * STEPS][RSLOT]; // depth-16 rings
    __shared__ __align__(16) float plds[2][2 * STEPS][PPITCH];  // waves 1,2 pre-gates

    const int tid = threadIdx.x;
    const int wv = tid / 64;
    const int lane = tid & 63;
    const long b_base = (long)blockIdx.x * G_B;

    {
        // stage x interleaved: xlds[2*t + g] = x[b_base+g][t]
        const float* xg = x + b_base * T_LEN;
        for (int i = tid; i < G_B * T_LEN; i += 192) {
            const int t = i & (T_LEN - 1);
            const int g = i >> 10;
            xlds[2 * t + g] = xg[i];
        }
        for (int i = tid; i < 3 * 2 * STEPS * RSLOT; i += 192)
            ((_Float16*)rings)[i] = (_Float16)0.0f;
    }

    const bool act = lane < G_B * HID;
    const int g = act ? (lane / HID) : 0;
    const int j = act ? (lane % HID) : 0;

    const float* whh = (wv == 0) ? whh0 : (wv == 1) ? whh1 : whh2;
    const float* wih = (wv == 0) ? wih0 : (wv == 1) ? wih1 : wih2;
    const float* bih = (wv == 0) ? bih0 : (wv == 1) ? bih1 : bih2;
    const float* bhh = (wv == 0) ? bhh0 : (wv == 1) ? bhh1 : bhh2;

    // All 4 gate rows (i,f,g,o) of unit j in VGPRs, pre-scaled by the
    // activation's log2 factor (i,f,o: -log2e; g: -2log2e).
    half2v Whh[4][10];
    float bias[4];
    float wx[4] = {0.f, 0.f, 0.f, 0.f};
#pragma unroll
    for (int gt = 0; gt < 4; ++gt) {
        const float sc = (gt == 2) ? N2LOG2E : NLOG2E;
        const int r = gt * HID + j;
#pragma unroll
        for (int k4 = 0; k4 < 5; ++k4) {
            float4 v = *(const float4*)(whh + r * HID + 4 * k4);
            Whh[gt][2 * k4]     = pack2(sc * v.x, sc * v.y);
            Whh[gt][2 * k4 + 1] = pack2(sc * v.z, sc * v.w);
        }
        bias[gt] = sc * (bih[r] + bhh[r]);
        if (wv == 0) wx[gt] = sc * wih[r];  // w_ih0 is (80,1)
    }

    // B fragments for the ih MFMA (waves 1,2): lane holds 8 contiguous k of
    // W_ih row n = t*16 + (lane&15), k-chunk = (lane>>4)*8, zero-padded k>=20.
    f16x8 WihB[5];
    if (wv > 0) {
        const int kc = (lane >> 4) * 8;
        const int col = lane & 15;
#pragma unroll
        for (int t = 0; t < 5; ++t) {
            const int n = t * 16 + col;           // 0..79
            const int gt = n / HID;               // gate of this column
            const float sc = (gt == 2) ? N2LOG2E : NLOG2E;
            f16x8 v;
#pragma unroll
            for (int e = 0; e < 8; ++e) {
                const int k = kc + e;
                const float w = (k < HID) ? wih[n * HID + k] : 0.f;
                v[e] = (_Float16)(sc * w);
            }
            WihB[t] = v;
        }
    }

    _Float16* const own_base = &rings[wv][0][0];
    const _Float16* const bel_base = (wv > 0) ? &rings[wv - 1][0][0]
                                              : &rings[0][0][0];
    float* const myp = &plds[(wv > 0) ? (wv - 1) : 0][0][0];

    float c = 0.0f;                       // cell state (own unit)
    // carried own-h partial: oA = bias + Whh.h(t-1); h(-1)=0 -> bias
    float oA[4] = {bias[0], bias[1], bias[2], bias[3]};

    __syncthreads();

    const int SS = T_LEN / STEPS;  // supersteps per wave

    for (int s = 0; s < SS + 2; ++s) {
        const int m = s - wv;
        if (m >= 0 && m < SS) {
            const int t0 = STEPS * m;
            const int hb = (m & 1) * (STEPS * RSLOT);  // ring half-buffer (halfs)

            if (wv > 0) {
                // ---- ih pre-gates for all 8 steps x 2 batches via MFMA ----
                const int ar = lane & 15;  // A row = (i = ar>>1, g = ar&1)
                const _Float16* ab = bel_base + hb + (ar >> 1) * RSLOT
                                   + (ar & 1) * 32 + (lane >> 4) * 8;
                const f16x8 af = *(const f16x8*)ab;
                const int crow = (lane >> 4) * 4;
                const int ccol = lane & 15;
                const f32x4 z = {0.f, 0.f, 0.f, 0.f};
#pragma unroll
                for (int t = 0; t < 5; ++t) {
                    f32x4 acc = __builtin_amdgcn_mfma_f32_16x16x32_f16(
                        af, WihB[t], z, 0, 0, 0);
#pragma unroll
                    for (int q = 0; q < 4; ++q)
                        myp[(crow + q) * PPITCH + t * 16 + ccol] = acc[q];
                }
            }

            // ---- serial chain: 8 steps ----
            const int qo = hb + g * 32;
#pragma unroll
            for (int i = 0; i < STEPS; ++i) {
                float p[4];
                if (wv == 0) {
                    const float xt = xlds[2 * (t0 + i) + g];
#pragma unroll
                    for (int gt = 0; gt < 4; ++gt)
                        p[gt] = oA[gt] + wx[gt] * xt;
                } else {
                    const float* pr = myp + (2 * i + g) * PPITCH + j;
#pragma unroll
                    for (int gt = 0; gt < 4; ++gt)
                        p[gt] = oA[gt] + pr[gt * HID];
                }
                const float ei = __builtin_exp2f(p[0]);
                const float ef = __builtin_exp2f(p[1]);
                const float eg = __builtin_exp2f(p[2]);
                const float eo = __builtin_exp2f(p[3]);
                const float sf = __builtin_amdgcn_rcpf(1.0f + ef);
                const float u  = (1.0f - eg) *
                    __builtin_amdgcn_rcpf((1.0f + ei) * (1.0f + eg));
                c = sf * c + u;                   // sigma(f)*c + sigma(i)*tanh(g)
                const float ec = __builtin_exp2f(N2LOG2E * c);
                const float hn = (1.0f - ec) *
                    __builtin_amdgcn_rcpf((1.0f + eo) * (1.0f + ec));
                _Float16* const wp = own_base + qo + i * RSLOT;
                if (act) wp[j] = (_Float16)hn;
                // own-h readback + dots (same-wave in-order DS, no sync)
                half2v ho[10];
                load_h20(wp, ho);
#pragma unroll
                for (int gt = 0; gt < 4; ++gt)
                    oA[gt] = dot20s(Whh[gt], ho, bias[gt]);
            }
        }
        __syncthreads();  // publish this superstep's 8 rows to the wave above
    }

    // FC epilogue: h2(T-1) lives in slot 15 (m=127 odd, i=7)
    if (wv == 2 && lane < 2 * G_B) {
        const int gg = lane >> 1, o = lane & 1;
        float acc = fcb[o];
        const _Float16* h2 = &rings[2][15][gg * 32];
#pragma unroll
        for (int k = 0; k < HID; ++k) {
            acc += fcw[o * HID + k] * (float)h2[k];
        }
        out[(b_base + gg) * 2 + o] = acc;
    }
}

extern "C" void kernel_launch(void* const* d_in, const int* in_sizes, int n_in,
                              void* d_out, int out_size, void* d_ws, size_t ws_size,
                              hipStream_t stream) {
    const float* x    = (const float*)d_in[0];
    const float* wih0 = (const float*)d_in[1];
    const float* whh0 = (const float*)d_in[2];
    const float* bih0 = (const float*)d_in[3];
    const float* bhh0 = (const float*)d_in[4];
    const float* wih1 = (const float*)d_in[5];
    const float* whh1 = (const float*)d_in[6];
    const float* bih1 = (const float*)d_in[7];
    const float* bhh1 = (const float*)d_in[8];
    const float* wih2 = (const float*)d_in[9];
    const float* whh2 = (const float*)d_in[10];
    const float* bih2 = (const float*)d_in[11];
    const float* bhh2 = (const float*)d_in[12];
    const float* fcw  = (const float*)d_in[13];
    const float* fcb  = (const float*)d_in[14];

    lstm3_r16<<<dim3(NBATCH / G_B), dim3(192), 0, stream>>>(
        x, wih0, whh0, bih0, bhh0,
        wih1, whh1, bih1, bhh1,
        wih2, whh2, bih2, bhh2,
        fcw, fcb, (float*)d_out);
}

// Round 3
// 557.780 us; speedup vs baseline: 1.2501x; 1.0288x over previous
//
#include <hip/hip_runtime.h>

typedef _Float16 half2v __attribute__((ext_vector_type(2)));
typedef _Float16 f16x8  __attribute__((ext_vector_type(8)));
typedef float    f32x4  __attribute__((ext_vector_type(4)));

#define T_LEN 1024
#define NBATCH 1024
#define HID 20
#define G_B 2       // batch elements per wave (lane groups of 20)
#define STEPS 16    // timesteps per superstep (one barrier per STEPS steps)
#define RSLOT 64    // halfs per ring timestep slot (2 batches x 32, zero-padded)
#define PPITCH 84   // pre-gate LDS row pitch in dwords (80 + 4 pad, mult of 4)

#if defined(__has_builtin)
#if __has_builtin(__builtin_amdgcn_fdot2)
#define HAVE_FDOT2 1
#endif
#endif

#define NLOG2E  -1.4426950408889634f   // -log2(e):  sigmoid gates
#define N2LOG2E -2.8853900817779268f   // -2log2(e): tanh gates

__device__ __forceinline__ float fdot2_(half2v a, half2v b, float c) {
#ifdef HAVE_FDOT2
    return __builtin_amdgcn_fdot2(a, b, c, false);
#else
    return c + (float)a[0] * (float)b[0] + (float)a[1] * (float)b[1];
#endif
}

__device__ __forceinline__ half2v pack2(float a, float b) {
    half2v r; r[0] = (_Float16)a; r[1] = (_Float16)b; return r;
}

// Load 20 f16 (one 32-half / 64B row, 16B-aligned) into 10 half2.
__device__ __forceinline__ void load_h20(const _Float16* row, half2v hp[10]) {
    uint4 q0 = *(const uint4*)(row);
    uint4 q1 = *(const uint4*)(row + 8);
    uint2 q2 = *(const uint2*)(row + 16);
    hp[0] = __builtin_bit_cast(half2v, q0.x);
    hp[1] = __builtin_bit_cast(half2v, q0.y);
    hp[2] = __builtin_bit_cast(half2v, q0.z);
    hp[3] = __builtin_bit_cast(half2v, q0.w);
    hp[4] = __builtin_bit_cast(half2v, q1.x);
    hp[5] = __builtin_bit_cast(half2v, q1.y);
    hp[6] = __builtin_bit_cast(half2v, q1.z);
    hp[7] = __builtin_bit_cast(half2v, q1.w);
    hp[8] = __builtin_bit_cast(half2v, q2.x);
    hp[9] = __builtin_bit_cast(half2v, q2.y);
}

// 20-element dot, two independent depth-5 chains, seeded with `seed`.
__device__ __forceinline__ float dot20s(const half2v W[10], const half2v h[10],
                                        float seed) {
    float a0 = seed, a1 = 0.f;
#pragma unroll
    for (int k = 0; k < 5; ++k) {
        a0 = fdot2_(W[k],     h[k],     a0);
        a1 = fdot2_(W[k + 5], h[k + 5], a1);
    }
    return a0 + a1;
}

// R18 = R17 with the pre-gate-buffer overflow fixed: plds needs NO
// double-buffering (produced and consumed by the same wave inside one
// barrier interval; same-wave DS is in-order), so the bogus pb offset that
// wrote past the slab (corrupting the next wave's buffer -> NaN) is gone.
// Structure: MFMA ih pre-gates w/ transposed C-scatter (col=j*4+gt -> one
// ds_read_b128 per step), all pre-reads hoisted (one lgkm wait/interval),
// STEPS=16 (half the barriers of R16). Serial recurrence math unchanged.
__global__ void __launch_bounds__(192, 2) lstm3_r18(
    const float* __restrict__ x,
    const float* __restrict__ wih0, const float* __restrict__ whh0,
    const float* __restrict__ bih0, const float* __restrict__ bhh0,
    const float* __restrict__ wih1, const float* __restrict__ whh1,
    const float* __restrict__ bih1, const float* __restrict__ bhh1,
    const float* __restrict__ wih2, const float* __restrict__ whh2,
    const float* __restrict__ bih2, const float* __restrict__ bhh2,
    const float* __restrict__ fcw, const float* __restrict__ fcb,
    float* __restrict__ out)
{
    __shared__ __align__(16) float xlds[G_B * T_LEN];             // [t][g]
    __shared__ __align__(16) _Float16 rings[3][2 * STEPS][RSLOT]; // double-buffered rings
    __shared__ __align__(16) float plds[2][2 * STEPS][PPITCH];    // waves 1,2 pre-gates

    const int tid = threadIdx.x;
    const int wv = tid / 64;
    const int lane = tid & 63;
    const long b_base = (long)blockIdx.x * G_B;

    {
        // stage x interleaved: xlds[2*t + g] = x[b_base+g][t]
        const float* xg = x + b_base * T_LEN;
        for (int i = tid; i < G_B * T_LEN; i += 192) {
            const int t = i & (T_LEN - 1);
            const int g = i >> 10;
            xlds[2 * t + g] = xg[i];
        }
        for (int i = tid; i < 3 * 2 * STEPS * RSLOT; i += 192)
            ((_Float16*)rings)[i] = (_Float16)0.0f;
    }

    const bool act = lane < G_B * HID;
    const int g = act ? (lane / HID) : 0;
    const int j = act ? (lane % HID) : 0;

    const float* whh = (wv == 0) ? whh0 : (wv == 1) ? whh1 : whh2;
    const float* wih = (wv == 0) ? wih0 : (wv == 1) ? wih1 : wih2;
    const float* bih = (wv == 0) ? bih0 : (wv == 1) ? bih1 : bih2;
    const float* bhh = (wv == 0) ? bhh0 : (wv == 1) ? bhh1 : bhh2;

    // All 4 gate rows (i,f,g,o) of unit j in VGPRs, pre-scaled by the
    // activation's log2 factor (i,f,o: -log2e; g: -2log2e).
    half2v Whh[4][10];
    float bias[4];
    float wx[4] = {0.f, 0.f, 0.f, 0.f};
#pragma unroll
    for (int gt = 0; gt < 4; ++gt) {
        const float sc = (gt == 2) ? N2LOG2E : NLOG2E;
        const int r = gt * HID + j;
#pragma unroll
        for (int k4 = 0; k4 < 5; ++k4) {
            float4 v = *(const float4*)(whh + r * HID + 4 * k4);
            Whh[gt][2 * k4]     = pack2(sc * v.x, sc * v.y);
            Whh[gt][2 * k4 + 1] = pack2(sc * v.z, sc * v.w);
        }
        bias[gt] = sc * (bih[r] + bhh[r]);
        if (wv == 0) wx[gt] = sc * wih[r];  // w_ih0 is (80,1)
    }

    // B fragments for the ih MFMA (waves 1,2): lane holds 8 contiguous k of
    // W_ih row n = t*16 + (lane&15), k-chunk = (lane>>4)*8, zero-padded k>=20.
    f16x8 WihB[5];
    int col4[5];  // transposed scatter column: (n%20)*4 + n/20
    if (wv > 0) {
        const int kc = (lane >> 4) * 8;
        const int col = lane & 15;
#pragma unroll
        for (int t = 0; t < 5; ++t) {
            const int n = t * 16 + col;           // 0..79
            const int gt = n / HID;               // gate of this column
            const float sc = (gt == 2) ? N2LOG2E : NLOG2E;
            f16x8 v;
#pragma unroll
            for (int e = 0; e < 8; ++e) {
                const int k = kc + e;
                const float w = (k < HID) ? wih[n * HID + k] : 0.f;
                v[e] = (_Float16)(sc * w);
            }
            WihB[t] = v;
            col4[t] = (n % HID) * 4 + gt;
        }
    }

    _Float16* const own_base = &rings[wv][0][0];
    const _Float16* const bel_base = (wv > 0) ? &rings[wv - 1][0][0]
                                              : &rings[0][0][0];
    float* const myp = &plds[(wv > 0) ? (wv - 1) : 0][0][0];
    // consumer pre-read base: row (2i+g), col 4j  (b128, 16B aligned)
    const float* const prb = myp + g * PPITCH + 4 * j;

    float c = 0.0f;                       // cell state (own unit)
    // carried own-h partial: oA = bias + Whh.h(t-1); h(-1)=0 -> bias
    float oA[4] = {bias[0], bias[1], bias[2], bias[3]};

    __syncthreads();

    const int SS = T_LEN / STEPS;  // supersteps per wave (64)

    for (int s = 0; s < SS + 2; ++s) {
        const int m = s - wv;
        if (m >= 0 && m < SS) {
            const int t0 = STEPS * m;
            const int hb = (m & 1) * (STEPS * RSLOT);  // ring half (halfs)

            float xr[STEPS];     // wave 0: hoisted x
            f32x4 pf[STEPS];     // waves 1,2: hoisted pre-gates

            if (wv > 0) {
                // ---- ih pre-gates for 16 steps x 2 batches: 10 MFMAs ----
                const int ar = lane & 15;  // A row within a 16-row half
                const int kc = (lane >> 4) * 8;
                const int crow = (lane >> 4) * 4;
                const f32x4 z = {0.f, 0.f, 0.f, 0.f};
#pragma unroll
                for (int h = 0; h < 2; ++h) {
                    // A half h: rows = (step = (ar>>1)+8h, batch = ar&1)
                    const _Float16* ab = bel_base + hb
                        + ((ar >> 1) + 8 * h) * RSLOT + (ar & 1) * 32 + kc;
                    const f16x8 af = *(const f16x8*)ab;
#pragma unroll
                    for (int t = 0; t < 5; ++t) {
                        f32x4 acc = __builtin_amdgcn_mfma_f32_16x16x32_f16(
                            af, WihB[t], z, 0, 0, 0);
                        // C row r (=crow+q) of half h -> pre-row r + 16h
                        // (pre-row 2*step+batch); col transposed to j*4+gt.
                        float* wrow = myp + (crow + 16 * h) * PPITCH + col4[t];
#pragma unroll
                        for (int q = 0; q < 4; ++q)
                            wrow[q * PPITCH] = acc[q];
                    }
                }
                // ---- hoisted pre-reads: 16 x b128, one wait ----
#pragma unroll
                for (int i = 0; i < STEPS; ++i)
                    pf[i] = *(const f32x4*)(prb + 2 * i * PPITCH);
            } else {
                const float* xp = xlds + 2 * t0 + g;
#pragma unroll
                for (int i = 0; i < STEPS; ++i)
                    xr[i] = xp[2 * i];
            }

            // ---- serial chain: 16 steps, zero non-recurrence LDS ----
            const int qo = hb + g * 32;
#pragma unroll
            for (int i = 0; i < STEPS; ++i) {
                float p[4];
                if (wv == 0) {
#pragma unroll
                    for (int gt = 0; gt < 4; ++gt)
                        p[gt] = oA[gt] + wx[gt] * xr[i];
                } else {
#pragma unroll
                    for (int gt = 0; gt < 4; ++gt)
                        p[gt] = oA[gt] + pf[i][gt];
                }
                const float ei = __builtin_exp2f(p[0]);
                const float ef = __builtin_exp2f(p[1]);
                const float eg = __builtin_exp2f(p[2]);
                const float eo = __builtin_exp2f(p[3]);
                const float sf = __builtin_amdgcn_rcpf(1.0f + ef);
                const float u  = (1.0f - eg) *
                    __builtin_amdgcn_rcpf((1.0f + ei) * (1.0f + eg));
                c = sf * c + u;                   // sigma(f)*c + sigma(i)*tanh(g)
                const float ec = __builtin_exp2f(N2LOG2E * c);
                const float hn = (1.0f - ec) *
                    __builtin_amdgcn_rcpf((1.0f + eo) * (1.0f + ec));
                _Float16* const wp = own_base + qo + i * RSLOT;
                if (act) wp[j] = (_Float16)hn;
                // own-h readback + dots (same-wave in-order DS, no sync)
                half2v ho[10];
                load_h20(wp, ho);
#pragma unroll
                for (int gt = 0; gt < 4; ++gt)
                    oA[gt] = dot20s(Whh[gt], ho, bias[gt]);
            }
        }
        __syncthreads();  // publish this superstep's 16 rows to the wave above
    }

    // FC epilogue: h2(T-1): m=63 (odd half), i=15 -> ring slot 31
    if (wv == 2 && lane < 2 * G_B) {
        const int gg = lane >> 1, o = lane & 1;
        float acc = fcb[o];
        const _Float16* h2 = &rings[2][2 * STEPS - 1][gg * 32];
#pragma unroll
        for (int k = 0; k < HID; ++k) {
            acc += fcw[o * HID + k] * (float)h2[k];
        }
        out[(b_base + gg) * 2 + o] = acc;
    }
}

extern "C" void kernel_launch(void* const* d_in, const int* in_sizes, int n_in,
                              void* d_out, int out_size, void* d_ws, size_t ws_size,
                              hipStream_t stream) {
    const float* x    = (const float*)d_in[0];
    const float* wih0 = (const float*)d_in[1];
    const float* whh0 = (const float*)d_in[2];
    const float* bih0 = (const float*)d_in[3];
    const float* bhh0 = (const float*)d_in[4];
    const float* wih1 = (const float*)d_in[5];
    const float* whh1 = (const float*)d_in[6];
    const float* bih1 = (const float*)d_in[7];
    const float* bhh1 = (const float*)d_in[8];
    const float* wih2 = (const float*)d_in[9];
    const float* whh2 = (const float*)d_in[10];
    const float* bih2 = (const float*)d_in[11];
    const float* bhh2 = (const float*)d_in[12];
    const float* fcw  = (const float*)d_in[13];
    const float* fcb  = (const float*)d_in[14];

    lstm3_r18<<<dim3(NBATCH / G_B), dim3(192), 0, stream>>>(
        x, wih0, whh0, bih0, bhh0,
        wih1, whh1, bih1, bhh1,
        wih2, whh2, bih2, bhh2,
        fcw, fcb, (float*)d_out);
}